// Round 5
// baseline (715.890 us; speedup 1.0000x reference)
//
#include <hip/hip_runtime.h>

typedef __attribute__((ext_vector_type(8))) short short8;
typedef __attribute__((ext_vector_type(4))) float f32x4;

__device__ __forceinline__ float b2f(unsigned short u) {
    unsigned int i = ((unsigned int)u) << 16;
    return __builtin_bit_cast(float, i);
}
__device__ __forceinline__ unsigned short f2b(float f) {
    unsigned int u = __builtin_bit_cast(unsigned int, f);
    unsigned int r = (u + 0x7fffu + ((u >> 16) & 1u)) >> 16;
    return (unsigned short)r;
}

// ------------- transpose + fp32->bf16 convert (weights, once per launch) ------
__global__ __launch_bounds__(256)
void transpose_f32_bf16(const float* __restrict__ in, unsigned short* __restrict__ out,
                        int R, int C) {
    __shared__ unsigned short t[32][33];
    const int r0 = blockIdx.y * 32, c0 = blockIdx.x * 32;
    const int tx = threadIdx.x & 31, ty = threadIdx.x >> 5;  // ty 0..7
    #pragma unroll
    for (int i = 0; i < 32; i += 8)
        t[ty + i][tx] = f2b(in[(size_t)(r0 + ty + i) * C + c0 + tx]);
    __syncthreads();
    #pragma unroll
    for (int i = 0; i < 32; i += 8)
        out[(size_t)(c0 + ty + i) * R + r0 + tx] = t[tx][ty + i];
}

// ------------- stage 1 GEMM: qkv(bf16) = x(fp32) @ WqkvT^T, MFMA 128x128 ------
__global__ __launch_bounds__(256, 2)
void gemm_a32_bt(const float* __restrict__ A,
                 const unsigned short* __restrict__ BT,
                 unsigned short* __restrict__ C,
                 int M, int N, int K) {
    __shared__ unsigned short As[128][40];
    __shared__ unsigned short Bs[128][40];
    const int tid  = threadIdx.x;
    const int wave = tid >> 6, lane = tid & 63;
    const int quad = lane >> 4, m16 = lane & 15;
    const int bm = blockIdx.y * 128;
    const int bn = blockIdx.x * 128;
    const int wm = (wave >> 1) * 64;
    const int wn = (wave & 1) * 64;
    const int r0 = tid >> 2;          // staging row 0..63
    const int c0 = (tid & 3) * 8;     // staging col chunk
    f32x4 acc[4][4] = {};
    const float* Ap = A + (size_t)(bm + r0) * K + c0;
    const unsigned short* Bp = BT + (size_t)(bn + r0) * K + c0;

    for (int k0 = 0; k0 < K; k0 += 32) {
        f32x4 a0l = *(const f32x4*)(Ap + k0);
        f32x4 a0h = *(const f32x4*)(Ap + k0 + 4);
        f32x4 a1l = *(const f32x4*)(Ap + (size_t)64 * K + k0);
        f32x4 a1h = *(const f32x4*)(Ap + (size_t)64 * K + k0 + 4);
        short8 b0 = *(const short8*)(Bp + k0);
        short8 b1 = *(const short8*)(Bp + (size_t)64 * K + k0);
        short8 a0, a1;
        #pragma unroll
        for (int j = 0; j < 4; ++j) {
            a0[j]     = (short)f2b(a0l[j]);
            a0[j + 4] = (short)f2b(a0h[j]);
            a1[j]     = (short)f2b(a1l[j]);
            a1[j + 4] = (short)f2b(a1h[j]);
        }
        __syncthreads();   // previous iter's frag reads done before overwrite
        *(short8*)&As[r0][c0]      = a0;
        *(short8*)&As[r0 + 64][c0] = a1;
        *(short8*)&Bs[r0][c0]      = b0;
        *(short8*)&Bs[r0 + 64][c0] = b1;
        __syncthreads();
        short8 af[4], bfr[4];
        #pragma unroll
        for (int i = 0; i < 4; ++i)
            af[i] = *(const short8*)&As[wm + i * 16 + m16][quad * 8];
        #pragma unroll
        for (int j = 0; j < 4; ++j)
            bfr[j] = *(const short8*)&Bs[wn + j * 16 + m16][quad * 8];
        #pragma unroll
        for (int i = 0; i < 4; ++i)
            #pragma unroll
            for (int j = 0; j < 4; ++j)
                acc[i][j] = __builtin_amdgcn_mfma_f32_16x16x32_bf16(af[i], bfr[j], acc[i][j], 0, 0, 0);
    }

    #pragma unroll
    for (int j = 0; j < 4; ++j) {
        const int col = bn + wn + j * 16 + m16;
        #pragma unroll
        for (int i = 0; i < 4; ++i) {
            #pragma unroll
            for (int r = 0; r < 4; ++r) {
                const int row = bm + wm + i * 16 + quad * 4 + r;
                C[(size_t)row * N + col] = f2b(acc[i][j][r]);
            }
        }
    }
}

// ------------- stage 5 GEMM: out(fp32) = O(bf16) @ WoutT^T + bout, MFMA -------
__global__ __launch_bounds__(256, 2)
void gemm_bt_f32out(const unsigned short* __restrict__ A,
                    const unsigned short* __restrict__ BT,
                    float* __restrict__ C,
                    const float* __restrict__ bias,
                    int M, int N, int K) {
    __shared__ unsigned short As[128][40];
    __shared__ unsigned short Bs[128][40];
    const int tid  = threadIdx.x;
    const int wave = tid >> 6, lane = tid & 63;
    const int quad = lane >> 4, m16 = lane & 15;
    const int bm = blockIdx.y * 128;
    const int bn = blockIdx.x * 128;
    const int wm = (wave >> 1) * 64;
    const int wn = (wave & 1) * 64;
    const int r0 = tid >> 2;
    const int c0 = (tid & 3) * 8;
    f32x4 acc[4][4] = {};
    const unsigned short* Ap = A + (size_t)(bm + r0) * K + c0;
    const unsigned short* Bp = BT + (size_t)(bn + r0) * K + c0;

    for (int k0 = 0; k0 < K; k0 += 32) {
        short8 a0 = *(const short8*)(Ap + k0);
        short8 a1 = *(const short8*)(Ap + (size_t)64 * K + k0);
        short8 b0 = *(const short8*)(Bp + k0);
        short8 b1 = *(const short8*)(Bp + (size_t)64 * K + k0);
        __syncthreads();
        *(short8*)&As[r0][c0]      = a0;
        *(short8*)&As[r0 + 64][c0] = a1;
        *(short8*)&Bs[r0][c0]      = b0;
        *(short8*)&Bs[r0 + 64][c0] = b1;
        __syncthreads();
        short8 af[4], bfr[4];
        #pragma unroll
        for (int i = 0; i < 4; ++i)
            af[i] = *(const short8*)&As[wm + i * 16 + m16][quad * 8];
        #pragma unroll
        for (int j = 0; j < 4; ++j)
            bfr[j] = *(const short8*)&Bs[wn + j * 16 + m16][quad * 8];
        #pragma unroll
        for (int i = 0; i < 4; ++i)
            #pragma unroll
            for (int j = 0; j < 4; ++j)
                acc[i][j] = __builtin_amdgcn_mfma_f32_16x16x32_bf16(af[i], bfr[j], acc[i][j], 0, 0, 0);
    }

    #pragma unroll
    for (int j = 0; j < 4; ++j) {
        const int col = bn + wn + j * 16 + m16;
        const float bv = bias ? bias[col] : 0.0f;
        #pragma unroll
        for (int i = 0; i < 4; ++i) {
            #pragma unroll
            for (int r = 0; r < 4; ++r) {
                const int row = bm + wm + i * 16 + quad * 4 + r;
                C[(size_t)row * N + col] = acc[i][j][r] + bv;
            }
        }
    }
}

// ---- stage 2: S[p][q] = sum_n k[n,p] q[n,q] per (b,h) + col sumsq, split-K ---
#define SPLIT 8
__global__ __launch_bounds__(256)
void kq_gram_b(const unsigned short* __restrict__ qkv,
               float* __restrict__ S, float* __restrict__ qn2, float* __restrict__ kn2) {
    const int bh = blockIdx.x / SPLIT;
    const int part = blockIdx.x % SPLIT;
    const int b = bh / 12, h = bh % 12;
    const int n0 = part * (4096 / SPLIT);      // 512 tokens per block
    __shared__ float Qs[64][65];
    __shared__ float Ks[64][65];
    const int tid = threadIdx.x;
    const int q0 = (tid & 15) * 4;
    const int p0 = (tid >> 4) * 4;
    float acc[4][4] = {};
    float qn[4] = {}, kn[4] = {};
    for (int nc = 0; nc < 512; nc += 64) {
        __syncthreads();
        #pragma unroll
        for (int t = 0; t < 16; ++t) {
            int idx = tid + t * 256;
            int r = idx >> 6, cc = idx & 63;
            const unsigned short* base = qkv + (size_t)(b * 4096 + n0 + nc + r) * 2304 + h * 64 + cc;
            Qs[r][cc] = b2f(base[0]);
            Ks[r][cc] = b2f(base[768]);
        }
        __syncthreads();
        for (int n = 0; n < 64; ++n) {
            float qv[4], kv[4];
            #pragma unroll
            for (int j = 0; j < 4; ++j) qv[j] = Qs[n][q0 + j];
            #pragma unroll
            for (int i = 0; i < 4; ++i) kv[i] = Ks[n][p0 + i];
            #pragma unroll
            for (int i = 0; i < 4; ++i)
                #pragma unroll
                for (int j = 0; j < 4; ++j)
                    acc[i][j] += kv[i] * qv[j];
            if (p0 == 0) {
                #pragma unroll
                for (int j = 0; j < 4; ++j) qn[j] += qv[j] * qv[j];
            }
            if (q0 == 0) {
                #pragma unroll
                for (int i = 0; i < 4; ++i) kn[i] += kv[i] * kv[i];
            }
        }
    }
    float* Sb = S + (size_t)bh * 4096;
    #pragma unroll
    for (int i = 0; i < 4; ++i)
        #pragma unroll
        for (int j = 0; j < 4; ++j)
            atomicAdd(&Sb[(p0 + i) * 64 + q0 + j], acc[i][j]);
    if (p0 == 0)
        #pragma unroll
        for (int j = 0; j < 4; ++j) atomicAdd(&qn2[bh * 64 + q0 + j], qn[j]);
    if (q0 == 0)
        #pragma unroll
        for (int i = 0; i < 4; ++i) atomicAdd(&kn2[bh * 64 + p0 + i], kn[i]);
}

// ---- stage 3: attn[p][q] = softmax_q( t*S[p][q]/(|k_p||q_q|) ), fp32 ---------
__global__ __launch_bounds__(64)
void softmax_naive(const float* __restrict__ S, const float* __restrict__ qn2,
                   const float* __restrict__ kn2, const float* __restrict__ temp,
                   float* __restrict__ attn) {
    const int bh = blockIdx.x, h = bh % 12, p = threadIdx.x;
    const float t = temp[h];
    const float knv = fmaxf(sqrtf(kn2[bh * 64 + p]), 1e-12f);
    const float* Sr = S + (size_t)bh * 4096 + p * 64;
    const float* qr = qn2 + bh * 64;
    float l[64];
    float mx = -1e30f;
    #pragma unroll
    for (int q = 0; q < 64; ++q) {
        const float qnv = fmaxf(sqrtf(qr[q]), 1e-12f);
        l[q] = t * Sr[q] / (knv * qnv);
        mx = fmaxf(mx, l[q]);
    }
    float sum = 0.f;
    #pragma unroll
    for (int q = 0; q < 64; ++q) { l[q] = __expf(l[q] - mx); sum += l[q]; }
    const float inv = 1.0f / sum;
    float* Ar = attn + (size_t)bh * 4096 + p * 64;
    #pragma unroll
    for (int q = 0; q < 64; ++q) Ar[q] = l[q] * inv;
}

// ---- stage 4: O[n][q] = sum_p v[n][p] * attn[p][q] -> bf16 O -----------------
__global__ __launch_bounds__(256)
void av_naive_b(const unsigned short* __restrict__ qkv, const float* __restrict__ attn,
                unsigned short* __restrict__ O) {
    const int bh = blockIdx.y, b = bh / 12, h = bh % 12;
    const int n0 = blockIdx.x * 64;
    __shared__ float At[64][65];
    const int tid = threadIdx.x;
    #pragma unroll
    for (int t = 0; t < 16; ++t) {
        int idx = tid + t * 256;
        At[idx >> 6][idx & 63] = attn[(size_t)bh * 4096 + idx];
    }
    __syncthreads();
    const int q = tid & 63, ni = tid >> 6;
    for (int it = 0; it < 16; ++it) {
        const int n = n0 + it * 4 + ni;
        const unsigned short* vrow = qkv + (size_t)(b * 4096 + n) * 2304 + 1536 + h * 64;
        float s = 0.f;
        #pragma unroll
        for (int p = 0; p < 64; ++p) s += b2f(vrow[p]) * At[p][q];
        O[(size_t)(b * 4096 + n) * 768 + h * 64 + q] = f2b(s);
    }
}

extern "C" void kernel_launch(void* const* d_in, const int* in_sizes, int n_in,
                              void* d_out, int out_size, void* d_ws, size_t ws_size,
                              hipStream_t stream) {
    // Select inputs by flat size (all distinct).
    const float *x = nullptr, *Wqkv = nullptr, *temp = nullptr, *Wout = nullptr, *bout = nullptr;
    for (int i = 0; i < n_in; ++i) {
        switch (in_sizes[i]) {
            case 25165824: x    = (const float*)d_in[i]; break;  // 8*4096*768
            case 1769472:  Wqkv = (const float*)d_in[i]; break;  // 768*2304
            case 12:       temp = (const float*)d_in[i]; break;  // (1,12,1,1)
            case 589824:   Wout = (const float*)d_in[i]; break;  // 768*768
            case 768:      bout = (const float*)d_in[i]; break;  // (768,)
        }
    }
    float* out = (float*)d_out;  // (8,4096,768) fp32

    char* ws = (char*)d_ws;
    unsigned short* WqkvT = (unsigned short*)(ws);                // 3,538,944 B
    unsigned short* WoutT = (unsigned short*)(ws + 3538944);      // 1,179,648 B
    const size_t base = 4718592;

    // Per-batch: qkv(bf16) 18,874,368 + O(bf16) 6,291,456 + attn 196,608 +
    //            S 196,608 + qn2 3,072 + kn2 3,072 = 25,565,184
    const size_t perb = 25565184;
    int c = 1;
    if      (base + 8 * perb <= ws_size) c = 8;
    else if (base + 4 * perb <= ws_size) c = 4;
    else if (base + 2 * perb <= ws_size) c = 2;

    char* ca = ws + base;
    unsigned short* qkv  = (unsigned short*)(ca);
    unsigned short* O    = (unsigned short*)(ca + (size_t)c * 18874368);
    float* attn          = (float*)(ca + (size_t)c * (18874368 + 6291456));
    char*  Sz            =         ca + (size_t)c * (18874368 + 6291456 + 196608);
    float* S             = (float*)Sz;
    float* qn2           = (float*)(Sz + (size_t)c * 196608);
    float* kn2           = (float*)(Sz + (size_t)c * (196608 + 3072));

    transpose_f32_bf16<<<dim3(2304 / 32, 768 / 32), 256, 0, stream>>>(Wqkv, WqkvT, 768, 2304);
    transpose_f32_bf16<<<dim3(768 / 32, 768 / 32), 256, 0, stream>>>(Wout, WoutT, 768, 768);

    for (int b0 = 0; b0 < 8; b0 += c) {
        const int nb = c;  // 8 % c == 0
        hipMemsetAsync(Sz, 0, (size_t)nb * (196608 + 3072 + 3072), stream);

        // stage 1: qkv = x @ Wqkv   (M=nb*4096, N=2304, K=768), fp32 A -> bf16
        gemm_a32_bt<<<dim3(2304 / 128, nb * 32), 256, 0, stream>>>(
            x + (size_t)b0 * 4096 * 768, WqkvT, qkv, nb * 4096, 2304, 768);

        // stage 2: per-(b,h) Gram + norms (fp32 accum)
        kq_gram_b<<<dim3(nb * 12 * SPLIT), 256, 0, stream>>>(qkv, S, qn2, kn2);

        // stage 3: scaled softmax -> attn fp32
        softmax_naive<<<dim3(nb * 12), 64, 0, stream>>>(S, qn2, kn2, temp, attn);

        // stage 4: O = V @ attn -> bf16
        av_naive_b<<<dim3(4096 / 64, nb * 12), 256, 0, stream>>>(qkv, attn, O);

        // stage 5: out = O @ Wout + bout -> fp32
        gemm_bt_f32out<<<dim3(768 / 128, nb * 32), 256, 0, stream>>>(
            O, WoutT, out + (size_t)b0 * 4096 * 768, bout, nb * 4096, 768, 768);
    }
}

// Round 6
// 539.706 us; speedup vs baseline: 1.3264x; 1.3264x over previous
//
#include <hip/hip_runtime.h>

typedef __attribute__((ext_vector_type(8))) short short8;
typedef __attribute__((ext_vector_type(4))) float f32x4;

__device__ __forceinline__ float b2f(unsigned short u) {
    unsigned int i = ((unsigned int)u) << 16;
    return __builtin_bit_cast(float, i);
}
__device__ __forceinline__ unsigned short f2b(float f) {
    unsigned int u = __builtin_bit_cast(unsigned int, f);
    unsigned int r = (u + 0x7fffu + ((u >> 16) & 1u)) >> 16;
    return (unsigned short)r;
}

// async 16B global->LDS copy; lds base must be wave-uniform (HW adds lane*16B)
__device__ __forceinline__ void async16(unsigned short* lds, const unsigned short* g) {
    __builtin_amdgcn_global_load_lds(
        (const __attribute__((address_space(1))) unsigned int*)g,
        (__attribute__((address_space(3))) unsigned int*)lds,
        16, 0, 0);
}

// ------------- x fp32 -> bf16 bulk convert (8 elts/thread) --------------------
__global__ __launch_bounds__(256)
void cvt_f32_bf16(const float* __restrict__ in, unsigned short* __restrict__ out,
                  long long n8) {
    const long long i = ((long long)blockIdx.x * 256 + threadIdx.x) * 8;
    if (i >= n8) return;
    f32x4 a = *(const f32x4*)(in + i);
    f32x4 b = *(const f32x4*)(in + i + 4);
    short8 o;
    #pragma unroll
    for (int j = 0; j < 4; ++j) { o[j] = (short)f2b(a[j]); o[j + 4] = (short)f2b(b[j]); }
    *(short8*)(out + i) = o;
}

// ------------- transpose + fp32->bf16 convert (weights, once per launch) ------
__global__ __launch_bounds__(256)
void transpose_f32_bf16(const float* __restrict__ in, unsigned short* __restrict__ out,
                        int R, int C) {
    __shared__ unsigned short t[32][33];
    const int r0 = blockIdx.y * 32, c0 = blockIdx.x * 32;
    const int tx = threadIdx.x & 31, ty = threadIdx.x >> 5;
    #pragma unroll
    for (int i = 0; i < 32; i += 8)
        t[ty + i][tx] = f2b(in[(size_t)(r0 + ty + i) * C + c0 + tx]);
    __syncthreads();
    #pragma unroll
    for (int i = 0; i < 32; i += 8)
        out[(size_t)(c0 + ty + i) * R + r0 + tx] = t[tx][ty + i];
}

// ------------- m97-style GEMM: C(MxN) = A(MxK) @ BT(NxK)^T, all bf16 ----------
// 128x128 tile, BK=32, unpadded LDS, global_load_lds width-16 staging.
__global__ __launch_bounds__(256, 2)
void gemm_bt_async(const unsigned short* __restrict__ A,
                   const unsigned short* __restrict__ BT,
                   unsigned short* __restrict__ C,
                   int M, int N, int K) {
    __shared__ unsigned short As[128 * 32];
    __shared__ unsigned short Bs[128 * 32];
    const int tid  = threadIdx.x;
    const int wave = tid >> 6, lane = tid & 63;
    const int quad = lane >> 4, m16 = lane & 15;
    const int bm = blockIdx.y * 128, bn = blockIdx.x * 128;
    const int wm = (wave >> 1) * 64, wn = (wave & 1) * 64;
    // staging: wave covers tile rows [wave*32, wave*32+32)
    const int srow = wave * 32 + (lane >> 2);
    const int scol = (lane & 3) * 8;
    const unsigned short* Ag = A + (size_t)(bm + srow) * K + scol;
    const unsigned short* Bg = BT + (size_t)(bn + srow) * K + scol;
    unsigned short* Asw = &As[(wave * 32) * 32];   // wave-uniform LDS base
    unsigned short* Bsw = &Bs[(wave * 32) * 32];
    f32x4 acc[4][4] = {};

    for (int k0 = 0; k0 < K; k0 += 32) {
        __syncthreads();                           // prev iter frag reads done
        async16(Asw,           Ag + k0);
        async16(Asw + 16 * 32, Ag + k0 + (size_t)16 * K);
        async16(Bsw,           Bg + k0);
        async16(Bsw + 16 * 32, Bg + k0 + (size_t)16 * K);
        __syncthreads();                           // staging landed (vmcnt drain)
        short8 af[4], bfr[4];
        #pragma unroll
        for (int i = 0; i < 4; ++i)
            af[i] = *(const short8*)&As[(wm + i * 16 + m16) * 32 + quad * 8];
        #pragma unroll
        for (int j = 0; j < 4; ++j)
            bfr[j] = *(const short8*)&Bs[(wn + j * 16 + m16) * 32 + quad * 8];
        #pragma unroll
        for (int i = 0; i < 4; ++i)
            #pragma unroll
            for (int j = 0; j < 4; ++j)
                acc[i][j] = __builtin_amdgcn_mfma_f32_16x16x32_bf16(af[i], bfr[j], acc[i][j], 0, 0, 0);
    }

    #pragma unroll
    for (int j = 0; j < 4; ++j) {
        const int col = bn + wn + j * 16 + m16;
        #pragma unroll
        for (int i = 0; i < 4; ++i)
            #pragma unroll
            for (int r = 0; r < 4; ++r) {
                const int row = bm + wm + i * 16 + quad * 4 + r;
                C[(size_t)row * N + col] = f2b(acc[i][j][r]);
            }
    }
}

// ------------- same, fp32 output + bias (stage 5 -> d_out) --------------------
__global__ __launch_bounds__(256, 2)
void gemm_bt_async_f32out(const unsigned short* __restrict__ A,
                          const unsigned short* __restrict__ BT,
                          float* __restrict__ C,
                          const float* __restrict__ bias,
                          int M, int N, int K) {
    __shared__ unsigned short As[128 * 32];
    __shared__ unsigned short Bs[128 * 32];
    const int tid  = threadIdx.x;
    const int wave = tid >> 6, lane = tid & 63;
    const int quad = lane >> 4, m16 = lane & 15;
    const int bm = blockIdx.y * 128, bn = blockIdx.x * 128;
    const int wm = (wave >> 1) * 64, wn = (wave & 1) * 64;
    const int srow = wave * 32 + (lane >> 2);
    const int scol = (lane & 3) * 8;
    const unsigned short* Ag = A + (size_t)(bm + srow) * K + scol;
    const unsigned short* Bg = BT + (size_t)(bn + srow) * K + scol;
    unsigned short* Asw = &As[(wave * 32) * 32];
    unsigned short* Bsw = &Bs[(wave * 32) * 32];
    f32x4 acc[4][4] = {};

    for (int k0 = 0; k0 < K; k0 += 32) {
        __syncthreads();
        async16(Asw,           Ag + k0);
        async16(Asw + 16 * 32, Ag + k0 + (size_t)16 * K);
        async16(Bsw,           Bg + k0);
        async16(Bsw + 16 * 32, Bg + k0 + (size_t)16 * K);
        __syncthreads();
        short8 af[4], bfr[4];
        #pragma unroll
        for (int i = 0; i < 4; ++i)
            af[i] = *(const short8*)&As[(wm + i * 16 + m16) * 32 + quad * 8];
        #pragma unroll
        for (int j = 0; j < 4; ++j)
            bfr[j] = *(const short8*)&Bs[(wn + j * 16 + m16) * 32 + quad * 8];
        #pragma unroll
        for (int i = 0; i < 4; ++i)
            #pragma unroll
            for (int j = 0; j < 4; ++j)
                acc[i][j] = __builtin_amdgcn_mfma_f32_16x16x32_bf16(af[i], bfr[j], acc[i][j], 0, 0, 0);
    }

    #pragma unroll
    for (int j = 0; j < 4; ++j) {
        const int col = bn + wn + j * 16 + m16;
        const float bv = bias[col];
        #pragma unroll
        for (int i = 0; i < 4; ++i)
            #pragma unroll
            for (int r = 0; r < 4; ++r) {
                const int row = bm + wm + i * 16 + quad * 4 + r;
                C[(size_t)row * N + col] = acc[i][j][r] + bv;
            }
    }
}

// ---- stage 2: S = K^T Q per (b,h) + col sumsq, split-K, bf16 vec loads -------
#define SPLIT 8
__global__ __launch_bounds__(256)
void kq_gram(const unsigned short* __restrict__ qkv,
             float* __restrict__ S, float* __restrict__ qn2, float* __restrict__ kn2) {
    const int bh = blockIdx.x / SPLIT;
    const int part = blockIdx.x % SPLIT;
    const int b = bh / 12, h = bh % 12;
    const int n0 = part * (4096 / SPLIT);
    __shared__ unsigned short Qs[64][72];
    __shared__ unsigned short Ks[64][72];
    const int tid = threadIdx.x;
    const int q0 = (tid & 15) * 4;
    const int p0 = (tid >> 4) * 4;
    float acc[4][4] = {};
    float qn[4] = {}, kn[4] = {};
    const int r = tid >> 2, cc = tid & 3;
    for (int nc = 0; nc < 512; nc += 64) {
        const unsigned short* qrow = qkv + (size_t)(b * 4096 + n0 + nc + r) * 2304 + h * 64;
        short8 v0 = *(const short8*)(qrow + cc * 8);
        short8 v1 = *(const short8*)(qrow + (cc + 4) * 8);
        short8 v2 = *(const short8*)(qrow + 768 + cc * 8);
        short8 v3 = *(const short8*)(qrow + 768 + (cc + 4) * 8);
        __syncthreads();
        *(short8*)&Qs[r][cc * 8]       = v0;
        *(short8*)&Qs[r][(cc + 4) * 8] = v1;
        *(short8*)&Ks[r][cc * 8]       = v2;
        *(short8*)&Ks[r][(cc + 4) * 8] = v3;
        __syncthreads();
        for (int n = 0; n < 64; ++n) {
            float qv[4], kv[4];
            #pragma unroll
            for (int j = 0; j < 4; ++j) qv[j] = b2f(Qs[n][q0 + j]);
            #pragma unroll
            for (int i = 0; i < 4; ++i) kv[i] = b2f(Ks[n][p0 + i]);
            #pragma unroll
            for (int i = 0; i < 4; ++i)
                #pragma unroll
                for (int j = 0; j < 4; ++j)
                    acc[i][j] += kv[i] * qv[j];
            if (p0 == 0) {
                #pragma unroll
                for (int j = 0; j < 4; ++j) qn[j] += qv[j] * qv[j];
            }
            if (q0 == 0) {
                #pragma unroll
                for (int i = 0; i < 4; ++i) kn[i] += kv[i] * kv[i];
            }
        }
    }
    float* Sb = S + (size_t)bh * 4096;
    #pragma unroll
    for (int i = 0; i < 4; ++i)
        #pragma unroll
        for (int j = 0; j < 4; ++j)
            atomicAdd(&Sb[(p0 + i) * 64 + q0 + j], acc[i][j]);
    if (p0 == 0)
        #pragma unroll
        for (int j = 0; j < 4; ++j) atomicAdd(&qn2[bh * 64 + q0 + j], qn[j]);
    if (q0 == 0)
        #pragma unroll
        for (int i = 0; i < 4; ++i) atomicAdd(&kn2[bh * 64 + p0 + i], kn[i]);
}

// ---- stage 3: logits = t*S/(|k||q|), row softmax, store attn^T (bf16) --------
__global__ __launch_bounds__(64)
void softmax_attn(const float* __restrict__ S, const float* __restrict__ qn2,
                  const float* __restrict__ kn2, const float* __restrict__ temp,
                  unsigned short* __restrict__ attnT) {
    const int bh = blockIdx.x, h = bh % 12, p = threadIdx.x;
    const float t = temp[h];
    const float knv = fmaxf(sqrtf(kn2[bh * 64 + p]), 1e-12f);
    const float* Sr = S + (size_t)bh * 4096 + p * 64;
    const float* qr = qn2 + bh * 64;
    float l[64];
    float mx = -1e30f;
    #pragma unroll
    for (int q = 0; q < 64; ++q) {
        const float qnv = fmaxf(sqrtf(qr[q]), 1e-12f);
        l[q] = t * Sr[q] / (knv * qnv);
        mx = fmaxf(mx, l[q]);
    }
    float sum = 0.f;
    #pragma unroll
    for (int q = 0; q < 64; ++q) { l[q] = __expf(l[q] - mx); sum += l[q]; }
    const float inv = 1.0f / sum;
    unsigned short* At = attnT + (size_t)bh * 4096;
    #pragma unroll
    for (int q = 0; q < 64; ++q) At[q * 64 + p] = f2b(l[q] * inv);
}

// ---- stage 4: O = V @ attn per (b,h), MFMA -----------------------------------
__global__ __launch_bounds__(256)
void av_gemm(const unsigned short* __restrict__ qkv, const unsigned short* __restrict__ attnT,
             unsigned short* __restrict__ O) {
    const int bh = blockIdx.y;
    const int b = bh / 12, h = bh % 12;
    const int n0 = blockIdx.x * 256;
    __shared__ unsigned short Vs[256][72];
    __shared__ unsigned short Ats[64][72];
    const int tid = threadIdx.x;
    const int wave = tid >> 6, lane = tid & 63;
    const int quad = lane >> 4, m16 = lane & 15;
    {
        const int r = tid >> 2, cc = tid & 3;
        const unsigned short* ap = attnT + (size_t)bh * 4096 + r * 64;
        *(short8*)&Ats[r][cc * 8]       = *(const short8*)(ap + cc * 8);
        *(short8*)&Ats[r][(cc + 4) * 8] = *(const short8*)(ap + (cc + 4) * 8);
        #pragma unroll
        for (int it = 0; it < 8; ++it) {
            const int idx = tid + it * 256;
            const int row = idx >> 3, c2 = (idx & 7) * 8;
            const unsigned short* vp = qkv + (size_t)(b * 4096 + n0 + row) * 2304 + 1536 + h * 64 + c2;
            *(short8*)&Vs[row][c2] = *(const short8*)vp;
        }
    }
    __syncthreads();
    f32x4 acc[4][4] = {};
    #pragma unroll
    for (int ks = 0; ks < 2; ++ks) {
        const int k0 = ks * 32;
        short8 af[4], bfr[4];
        #pragma unroll
        for (int i = 0; i < 4; ++i)
            af[i] = *(const short8*)&Vs[wave * 64 + i * 16 + m16][k0 + quad * 8];
        #pragma unroll
        for (int j = 0; j < 4; ++j)
            bfr[j] = *(const short8*)&Ats[j * 16 + m16][k0 + quad * 8];
        #pragma unroll
        for (int i = 0; i < 4; ++i)
            #pragma unroll
            for (int j = 0; j < 4; ++j)
                acc[i][j] = __builtin_amdgcn_mfma_f32_16x16x32_bf16(af[i], bfr[j], acc[i][j], 0, 0, 0);
    }
    #pragma unroll
    for (int i = 0; i < 4; ++i)
        #pragma unroll
        for (int j = 0; j < 4; ++j)
            #pragma unroll
            for (int r = 0; r < 4; ++r) {
                const int row = n0 + wave * 64 + i * 16 + quad * 4 + r;
                O[(size_t)(b * 4096 + row) * 768 + h * 64 + j * 16 + m16] = f2b(acc[i][j][r]);
            }
}

extern "C" void kernel_launch(void* const* d_in, const int* in_sizes, int n_in,
                              void* d_out, int out_size, void* d_ws, size_t ws_size,
                              hipStream_t stream) {
    const float *x = nullptr, *Wqkv = nullptr, *temp = nullptr, *Wout = nullptr, *bout = nullptr;
    for (int i = 0; i < n_in; ++i) {
        switch (in_sizes[i]) {
            case 25165824: x    = (const float*)d_in[i]; break;  // 8*4096*768
            case 1769472:  Wqkv = (const float*)d_in[i]; break;  // 768*2304
            case 12:       temp = (const float*)d_in[i]; break;  // (1,12,1,1)
            case 589824:   Wout = (const float*)d_in[i]; break;  // 768*768
            case 768:      bout = (const float*)d_in[i]; break;  // (768,)
        }
    }
    float* out = (float*)d_out;  // (8,4096,768) fp32

    char* ws = (char*)d_ws;
    unsigned short* WqkvT = (unsigned short*)(ws);                // 3,538,944 B
    unsigned short* WoutT = (unsigned short*)(ws + 3538944);      // 1,179,648 B
    const size_t base = 4718592;

    // Per-batch: xb 6,291,456 + qkv 18,874,368 + O 6,291,456 + attnT 98,304 +
    //            S 196,608 + qn2 3,072 + kn2 3,072 = 31,758,336
    const size_t perb = 31758336;
    int c = 1;
    if      (base + 8 * perb <= ws_size) c = 8;
    else if (base + 4 * perb <= ws_size) c = 4;
    else if (base + 2 * perb <= ws_size) c = 2;

    char* ca = ws + base;
    unsigned short* xb    = (unsigned short*)(ca);
    unsigned short* qkv   = (unsigned short*)(ca + (size_t)c * 6291456);
    unsigned short* O     = (unsigned short*)(ca + (size_t)c * 25165824);
    unsigned short* attnT = (unsigned short*)(ca + (size_t)c * 31457280);
    char*  Sz             =                   ca + (size_t)c * 31555584;
    float* S              = (float*)Sz;
    float* qn2            = (float*)(Sz + (size_t)c * 196608);
    float* kn2            = (float*)(Sz + (size_t)c * (196608 + 3072));

    transpose_f32_bf16<<<dim3(2304 / 32, 768 / 32), 256, 0, stream>>>(Wqkv, WqkvT, 768, 2304);
    transpose_f32_bf16<<<dim3(768 / 32, 768 / 32), 256, 0, stream>>>(Wout, WoutT, 768, 768);

    for (int b0 = 0; b0 < 8; b0 += c) {
        const int nb = c;  // 8 % c == 0
        hipMemsetAsync(Sz, 0, (size_t)nb * (196608 + 3072 + 3072), stream);

        // stage 0: x chunk -> bf16
        const long long n8 = (long long)nb * 3145728;
        cvt_f32_bf16<<<dim3((unsigned)(n8 / 8 / 256)), 256, 0, stream>>>(
            x + (size_t)b0 * 3145728, xb, n8);

        // stage 1: qkv = xb @ WqkvT^T  (M=nb*4096, N=2304, K=768)
        gemm_bt_async<<<dim3(2304 / 128, nb * 32), 256, 0, stream>>>(
            xb, WqkvT, qkv, nb * 4096, 2304, 768);

        // stage 2: per-(b,h) Gram + norms
        kq_gram<<<dim3(nb * 12 * SPLIT), 256, 0, stream>>>(qkv, S, qn2, kn2);

        // stage 3: scaled softmax -> attn^T bf16
        softmax_attn<<<dim3(nb * 12), 64, 0, stream>>>(S, qn2, kn2, temp, attnT);

        // stage 4: O = V @ attn -> bf16
        av_gemm<<<dim3(4096 / 256, nb * 12), 256, 0, stream>>>(qkv, attnT, O);

        // stage 5: out = O @ WoutT^T + bout -> fp32
        gemm_bt_async_f32out<<<dim3(768 / 128, nb * 32), 256, 0, stream>>>(
            O, WoutT, out + (size_t)b0 * 3145728, bout, nb * 4096, 768, 768);
    }
}

// Round 7
// 538.256 us; speedup vs baseline: 1.3300x; 1.0027x over previous
//
#include <hip/hip_runtime.h>

typedef __attribute__((ext_vector_type(8))) short short8;
typedef __attribute__((ext_vector_type(4))) unsigned short ushort4v;
typedef __attribute__((ext_vector_type(4))) float f32x4;

__device__ __forceinline__ float b2f(unsigned short u) {
    unsigned int i = ((unsigned int)u) << 16;
    return __builtin_bit_cast(float, i);
}
__device__ __forceinline__ unsigned short f2b(float f) {
    unsigned int u = __builtin_bit_cast(unsigned int, f);
    unsigned int r = (u + 0x7fffu + ((u >> 16) & 1u)) >> 16;
    return (unsigned short)r;
}

// async 16B global->LDS copy; lds base must be wave-uniform (HW adds lane*16B)
__device__ __forceinline__ void async16(unsigned short* lds, const unsigned short* g) {
    __builtin_amdgcn_global_load_lds(
        (const __attribute__((address_space(1))) unsigned int*)g,
        (__attribute__((address_space(3))) unsigned int*)lds,
        16, 0, 0);
}

// XCD-aware block swizzle: flat id -> (bx, by) such that each XCD (id%8,
// assuming round-robin dispatch) owns an exclusive band of row-panels and
// walks all columns of a panel consecutively (A-panel stays in its L2).
// Requires gridDim.y % 8 == 0. Pure permutation -> correctness-neutral.
__device__ __forceinline__ void xcd_swizzle(int& bx, int& by) {
    const int nx = gridDim.x;
    const int rows_per_xcd = gridDim.y >> 3;
    const int flat = blockIdx.y * nx + blockIdx.x;
    const int xcd = flat & 7;
    const int i = flat >> 3;
    by = xcd * rows_per_xcd + i / nx;
    bx = i % nx;
}

// ------------- x fp32 -> bf16 bulk convert (8 elts/thread) --------------------
__global__ __launch_bounds__(256)
void cvt_f32_bf16(const float* __restrict__ in, unsigned short* __restrict__ out,
                  long long n8) {
    const long long i = ((long long)blockIdx.x * 256 + threadIdx.x) * 8;
    if (i >= n8) return;
    f32x4 a = *(const f32x4*)(in + i);
    f32x4 b = *(const f32x4*)(in + i + 4);
    short8 o;
    #pragma unroll
    for (int j = 0; j < 4; ++j) { o[j] = (short)f2b(a[j]); o[j + 4] = (short)f2b(b[j]); }
    *(short8*)(out + i) = o;
}

// ------------- transpose + fp32->bf16 convert (weights, once per launch) ------
__global__ __launch_bounds__(256)
void transpose_f32_bf16(const float* __restrict__ in, unsigned short* __restrict__ out,
                        int R, int C) {
    __shared__ unsigned short t[32][33];
    const int r0 = blockIdx.y * 32, c0 = blockIdx.x * 32;
    const int tx = threadIdx.x & 31, ty = threadIdx.x >> 5;
    #pragma unroll
    for (int i = 0; i < 32; i += 8)
        t[ty + i][tx] = f2b(in[(size_t)(r0 + ty + i) * C + c0 + tx]);
    __syncthreads();
    #pragma unroll
    for (int i = 0; i < 32; i += 8)
        out[(size_t)(c0 + ty + i) * R + r0 + tx] = t[tx][ty + i];
}

// ------------- m97-style GEMM: C(MxN) = A(MxK) @ BT(NxK)^T, all bf16 ----------
__global__ __launch_bounds__(256, 2)
void gemm_bt_async(const unsigned short* __restrict__ A,
                   const unsigned short* __restrict__ BT,
                   unsigned short* __restrict__ C,
                   int M, int N, int K) {
    __shared__ unsigned short As[128 * 32];
    __shared__ unsigned short Bs[128 * 32];
    int bxi, byi;
    xcd_swizzle(bxi, byi);
    const int tid  = threadIdx.x;
    const int wave = tid >> 6, lane = tid & 63;
    const int quad = lane >> 4, m16 = lane & 15;
    const int bm = byi * 128, bn = bxi * 128;
    const int wm = (wave >> 1) * 64, wn = (wave & 1) * 64;
    const int srow = wave * 32 + (lane >> 2);
    const int scol = (lane & 3) * 8;
    const unsigned short* Ag = A + (size_t)(bm + srow) * K + scol;
    const unsigned short* Bg = BT + (size_t)(bn + srow) * K + scol;
    unsigned short* Asw = &As[(wave * 32) * 32];
    unsigned short* Bsw = &Bs[(wave * 32) * 32];
    f32x4 acc[4][4] = {};

    for (int k0 = 0; k0 < K; k0 += 32) {
        __syncthreads();
        async16(Asw,           Ag + k0);
        async16(Asw + 16 * 32, Ag + k0 + (size_t)16 * K);
        async16(Bsw,           Bg + k0);
        async16(Bsw + 16 * 32, Bg + k0 + (size_t)16 * K);
        __syncthreads();
        short8 af[4], bfr[4];
        #pragma unroll
        for (int i = 0; i < 4; ++i)
            af[i] = *(const short8*)&As[(wm + i * 16 + m16) * 32 + quad * 8];
        #pragma unroll
        for (int j = 0; j < 4; ++j)
            bfr[j] = *(const short8*)&Bs[(wn + j * 16 + m16) * 32 + quad * 8];
        #pragma unroll
        for (int i = 0; i < 4; ++i)
            #pragma unroll
            for (int j = 0; j < 4; ++j)
                acc[i][j] = __builtin_amdgcn_mfma_f32_16x16x32_bf16(af[i], bfr[j], acc[i][j], 0, 0, 0);
    }

    #pragma unroll
    for (int j = 0; j < 4; ++j) {
        const int col = bn + wn + j * 16 + m16;
        #pragma unroll
        for (int i = 0; i < 4; ++i)
            #pragma unroll
            for (int r = 0; r < 4; ++r) {
                const int row = bm + wm + i * 16 + quad * 4 + r;
                C[(size_t)row * N + col] = f2b(acc[i][j][r]);
            }
    }
}

// ------------- same, fp32 output + bias (stage 5 -> d_out) --------------------
__global__ __launch_bounds__(256, 2)
void gemm_bt_async_f32out(const unsigned short* __restrict__ A,
                          const unsigned short* __restrict__ BT,
                          float* __restrict__ C,
                          const float* __restrict__ bias,
                          int M, int N, int K) {
    __shared__ unsigned short As[128 * 32];
    __shared__ unsigned short Bs[128 * 32];
    int bxi, byi;
    xcd_swizzle(bxi, byi);
    const int tid  = threadIdx.x;
    const int wave = tid >> 6, lane = tid & 63;
    const int quad = lane >> 4, m16 = lane & 15;
    const int bm = byi * 128, bn = bxi * 128;
    const int wm = (wave >> 1) * 64, wn = (wave & 1) * 64;
    const int srow = wave * 32 + (lane >> 2);
    const int scol = (lane & 3) * 8;
    const unsigned short* Ag = A + (size_t)(bm + srow) * K + scol;
    const unsigned short* Bg = BT + (size_t)(bn + srow) * K + scol;
    unsigned short* Asw = &As[(wave * 32) * 32];
    unsigned short* Bsw = &Bs[(wave * 32) * 32];
    f32x4 acc[4][4] = {};

    for (int k0 = 0; k0 < K; k0 += 32) {
        __syncthreads();
        async16(Asw,           Ag + k0);
        async16(Asw + 16 * 32, Ag + k0 + (size_t)16 * K);
        async16(Bsw,           Bg + k0);
        async16(Bsw + 16 * 32, Bg + k0 + (size_t)16 * K);
        __syncthreads();
        short8 af[4], bfr[4];
        #pragma unroll
        for (int i = 0; i < 4; ++i)
            af[i] = *(const short8*)&As[(wm + i * 16 + m16) * 32 + quad * 8];
        #pragma unroll
        for (int j = 0; j < 4; ++j)
            bfr[j] = *(const short8*)&Bs[(wn + j * 16 + m16) * 32 + quad * 8];
        #pragma unroll
        for (int i = 0; i < 4; ++i)
            #pragma unroll
            for (int j = 0; j < 4; ++j)
                acc[i][j] = __builtin_amdgcn_mfma_f32_16x16x32_bf16(af[i], bfr[j], acc[i][j], 0, 0, 0);
    }

    #pragma unroll
    for (int j = 0; j < 4; ++j) {
        const int col = bn + wn + j * 16 + m16;
        const float bv = bias[col];
        #pragma unroll
        for (int i = 0; i < 4; ++i)
            #pragma unroll
            for (int r = 0; r < 4; ++r) {
                const int row = bm + wm + i * 16 + quad * 4 + r;
                C[(size_t)row * N + col] = acc[i][j][r] + bv;
            }
    }
}

// ---- stage 2: S = K^T Q per (b,h) + col sumsq, split-K, b64 LDS reads --------
#define SPLIT 16
__global__ __launch_bounds__(256)
void kq_gram(const unsigned short* __restrict__ qkv,
             float* __restrict__ S, float* __restrict__ qn2, float* __restrict__ kn2) {
    const int bh = blockIdx.x / SPLIT;
    const int part = blockIdx.x % SPLIT;
    const int b = bh / 12, h = bh % 12;
    const int n0 = part * (4096 / SPLIT);      // 256 tokens per block
    __shared__ unsigned short Qs[64][72];
    __shared__ unsigned short Ks[64][72];
    const int tid = threadIdx.x;
    const int q0 = (tid & 15) * 4;
    const int p0 = (tid >> 4) * 4;
    float acc[4][4] = {};
    float qn[4] = {}, kn[4] = {};
    const int r = tid >> 2, cc = tid & 3;
    for (int nc = 0; nc < 256; nc += 64) {
        const unsigned short* qrow = qkv + (size_t)(b * 4096 + n0 + nc + r) * 2304 + h * 64;
        short8 v0 = *(const short8*)(qrow + cc * 8);
        short8 v1 = *(const short8*)(qrow + (cc + 4) * 8);
        short8 v2 = *(const short8*)(qrow + 768 + cc * 8);
        short8 v3 = *(const short8*)(qrow + 768 + (cc + 4) * 8);
        __syncthreads();
        *(short8*)&Qs[r][cc * 8]       = v0;
        *(short8*)&Qs[r][(cc + 4) * 8] = v1;
        *(short8*)&Ks[r][cc * 8]       = v2;
        *(short8*)&Ks[r][(cc + 4) * 8] = v3;
        __syncthreads();
        for (int n = 0; n < 64; ++n) {
            const ushort4v qu = *(const ushort4v*)&Qs[n][q0];   // one ds_read_b64
            const ushort4v ku = *(const ushort4v*)&Ks[n][p0];   // one ds_read_b64
            float qv[4], kv[4];
            #pragma unroll
            for (int j = 0; j < 4; ++j) qv[j] = b2f(qu[j]);
            #pragma unroll
            for (int i = 0; i < 4; ++i) kv[i] = b2f(ku[i]);
            #pragma unroll
            for (int i = 0; i < 4; ++i)
                #pragma unroll
                for (int j = 0; j < 4; ++j)
                    acc[i][j] += kv[i] * qv[j];
            if (p0 == 0) {
                #pragma unroll
                for (int j = 0; j < 4; ++j) qn[j] += qv[j] * qv[j];
            }
            if (q0 == 0) {
                #pragma unroll
                for (int i = 0; i < 4; ++i) kn[i] += kv[i] * kv[i];
            }
        }
    }
    float* Sb = S + (size_t)bh * 4096;
    #pragma unroll
    for (int i = 0; i < 4; ++i)
        #pragma unroll
        for (int j = 0; j < 4; ++j)
            atomicAdd(&Sb[(p0 + i) * 64 + q0 + j], acc[i][j]);
    if (p0 == 0)
        #pragma unroll
        for (int j = 0; j < 4; ++j) atomicAdd(&qn2[bh * 64 + q0 + j], qn[j]);
    if (q0 == 0)
        #pragma unroll
        for (int i = 0; i < 4; ++i) atomicAdd(&kn2[bh * 64 + p0 + i], kn[i]);
}

// ---- stage 3: logits = t*S/(|k||q|), row softmax, store attn^T (bf16) --------
__global__ __launch_bounds__(64)
void softmax_attn(const float* __restrict__ S, const float* __restrict__ qn2,
                  const float* __restrict__ kn2, const float* __restrict__ temp,
                  unsigned short* __restrict__ attnT) {
    const int bh = blockIdx.x, h = bh % 12, p = threadIdx.x;
    const float t = temp[h];
    const float knv = fmaxf(sqrtf(kn2[bh * 64 + p]), 1e-12f);
    const float* Sr = S + (size_t)bh * 4096 + p * 64;
    const float* qr = qn2 + bh * 64;
    float l[64];
    float mx = -1e30f;
    #pragma unroll
    for (int q = 0; q < 64; ++q) {
        const float qnv = fmaxf(sqrtf(qr[q]), 1e-12f);
        l[q] = t * Sr[q] / (knv * qnv);
        mx = fmaxf(mx, l[q]);
    }
    float sum = 0.f;
    #pragma unroll
    for (int q = 0; q < 64; ++q) { l[q] = __expf(l[q] - mx); sum += l[q]; }
    const float inv = 1.0f / sum;
    unsigned short* At = attnT + (size_t)bh * 4096;
    #pragma unroll
    for (int q = 0; q < 64; ++q) At[q * 64 + p] = f2b(l[q] * inv);
}

// ---- stage 4: O = V @ attn per (b,h), MFMA -----------------------------------
__global__ __launch_bounds__(256)
void av_gemm(const unsigned short* __restrict__ qkv, const unsigned short* __restrict__ attnT,
             unsigned short* __restrict__ O) {
    const int bh = blockIdx.y;
    const int b = bh / 12, h = bh % 12;
    const int n0 = blockIdx.x * 256;
    __shared__ unsigned short Vs[256][72];
    __shared__ unsigned short Ats[64][72];
    const int tid = threadIdx.x;
    const int wave = tid >> 6, lane = tid & 63;
    const int quad = lane >> 4, m16 = lane & 15;
    {
        const int r = tid >> 2, cc = tid & 3;
        const unsigned short* ap = attnT + (size_t)bh * 4096 + r * 64;
        *(short8*)&Ats[r][cc * 8]       = *(const short8*)(ap + cc * 8);
        *(short8*)&Ats[r][(cc + 4) * 8] = *(const short8*)(ap + (cc + 4) * 8);
        #pragma unroll
        for (int it = 0; it < 8; ++it) {
            const int idx = tid + it * 256;
            const int row = idx >> 3, c2 = (idx & 7) * 8;
            const unsigned short* vp = qkv + (size_t)(b * 4096 + n0 + row) * 2304 + 1536 + h * 64 + c2;
            *(short8*)&Vs[row][c2] = *(const short8*)vp;
        }
    }
    __syncthreads();
    f32x4 acc[4][4] = {};
    #pragma unroll
    for (int ks = 0; ks < 2; ++ks) {
        const int k0 = ks * 32;
        short8 af[4], bfr[4];
        #pragma unroll
        for (int i = 0; i < 4; ++i)
            af[i] = *(const short8*)&Vs[wave * 64 + i * 16 + m16][k0 + quad * 8];
        #pragma unroll
        for (int j = 0; j < 4; ++j)
            bfr[j] = *(const short8*)&Ats[j * 16 + m16][k0 + quad * 8];
        #pragma unroll
        for (int i = 0; i < 4; ++i)
            #pragma unroll
            for (int j = 0; j < 4; ++j)
                acc[i][j] = __builtin_amdgcn_mfma_f32_16x16x32_bf16(af[i], bfr[j], acc[i][j], 0, 0, 0);
    }
    #pragma unroll
    for (int i = 0; i < 4; ++i)
        #pragma unroll
        for (int j = 0; j < 4; ++j)
            #pragma unroll
            for (int r = 0; r < 4; ++r) {
                const int row = n0 + wave * 64 + i * 16 + quad * 4 + r;
                O[(size_t)(b * 4096 + row) * 768 + h * 64 + j * 16 + m16] = f2b(acc[i][j][r]);
            }
}

extern "C" void kernel_launch(void* const* d_in, const int* in_sizes, int n_in,
                              void* d_out, int out_size, void* d_ws, size_t ws_size,
                              hipStream_t stream) {
    const float *x = nullptr, *Wqkv = nullptr, *temp = nullptr, *Wout = nullptr, *bout = nullptr;
    for (int i = 0; i < n_in; ++i) {
        switch (in_sizes[i]) {
            case 25165824: x    = (const float*)d_in[i]; break;  // 8*4096*768
            case 1769472:  Wqkv = (const float*)d_in[i]; break;  // 768*2304
            case 12:       temp = (const float*)d_in[i]; break;  // (1,12,1,1)
            case 589824:   Wout = (const float*)d_in[i]; break;  // 768*768
            case 768:      bout = (const float*)d_in[i]; break;  // (768,)
        }
    }
    float* out = (float*)d_out;  // (8,4096,768) fp32

    char* ws = (char*)d_ws;
    unsigned short* WqkvT = (unsigned short*)(ws);                // 3,538,944 B
    unsigned short* WoutT = (unsigned short*)(ws + 3538944);      // 1,179,648 B
    const size_t base = 4718592;

    // Per-batch: xb 6,291,456 + qkv 18,874,368 + O 6,291,456 + attnT 98,304 +
    //            S 196,608 + qn2 3,072 + kn2 3,072 = 31,758,336
    const size_t perb = 31758336;
    int c = 1;
    if      (base + 8 * perb <= ws_size) c = 8;
    else if (base + 4 * perb <= ws_size) c = 4;
    else if (base + 2 * perb <= ws_size) c = 2;

    char* ca = ws + base;
    unsigned short* xb    = (unsigned short*)(ca);
    unsigned short* qkv   = (unsigned short*)(ca + (size_t)c * 6291456);
    unsigned short* O     = (unsigned short*)(ca + (size_t)c * 25165824);
    unsigned short* attnT = (unsigned short*)(ca + (size_t)c * 31457280);
    char*  Sz             =                   ca + (size_t)c * 31555584;
    float* S              = (float*)Sz;
    float* qn2            = (float*)(Sz + (size_t)c * 196608);
    float* kn2            = (float*)(Sz + (size_t)c * (196608 + 3072));

    transpose_f32_bf16<<<dim3(2304 / 32, 768 / 32), 256, 0, stream>>>(Wqkv, WqkvT, 768, 2304);
    transpose_f32_bf16<<<dim3(768 / 32, 768 / 32), 256, 0, stream>>>(Wout, WoutT, 768, 768);

    for (int b0 = 0; b0 < 8; b0 += c) {
        const int nb = c;  // 8 % c == 0
        hipMemsetAsync(Sz, 0, (size_t)nb * (196608 + 3072 + 3072), stream);

        // stage 0: x chunk -> bf16
        const long long n8 = (long long)nb * 3145728;
        cvt_f32_bf16<<<dim3((unsigned)(n8 / 8 / 256)), 256, 0, stream>>>(
            x + (size_t)b0 * 3145728, xb, n8);

        // stage 1: qkv = xb @ WqkvT^T  (M=nb*4096, N=2304, K=768)
        gemm_bt_async<<<dim3(2304 / 128, nb * 32), 256, 0, stream>>>(
            xb, WqkvT, qkv, nb * 4096, 2304, 768);

        // stage 2: per-(b,h) Gram + norms
        kq_gram<<<dim3(nb * 12 * SPLIT), 256, 0, stream>>>(qkv, S, qn2, kn2);

        // stage 3: scaled softmax -> attn^T bf16
        softmax_attn<<<dim3(nb * 12), 64, 0, stream>>>(S, qn2, kn2, temp, attnT);

        // stage 4: O = V @ attn -> bf16
        av_gemm<<<dim3(4096 / 256, nb * 12), 256, 0, stream>>>(qkv, attnT, O);

        // stage 5: out = O @ WoutT^T + bout -> fp32
        gemm_bt_async_f32out<<<dim3(768 / 128, nb * 32), 256, 0, stream>>>(
            O, WoutT, out + (size_t)b0 * 3145728, bout, nb * 4096, 768, 768);
    }
}